// Round 5
// baseline (206.037 us; speedup 1.0000x reference)
//
#include <hip/hip_runtime.h>

#define F_DIM 128
#define TE_DIM 32
#define DD 160
#define NB 4096
#define KK 64
#define TPB 2          // targets per attn block (2 waves each)
#define XR_STRIDE 132  // halves; 264 B row: half2 reads conflict-free
#define TE_STRIDE 34   // halves; 68 B row: dword reads 17*lane mod 32 -> free

// ws layout (float offsets). Total 1366528 floats = 5.47 MB of d_ws.
#define WS_M    0          // [160][160]  (Wk^T Wq) / sqrt(160)
#define WS_V2   25600      // [160][160]  out_w @ Wv
#define WS_C    51200      // [160]       (Wk^T bq) / sqrt(160)
#define WS_U    51360      // [160]       (Wq^T bk) / sqrt(160)
#define WS_B2   51520      // [160]       out_w @ bv + out_b
#define WS_S0   51680      // [1]         (bq . bk) / sqrt(160)
#define WS_WTOT 51681
#define WS_QT   51712      // [4096][160] q_tilde
#define WS_SBK  707072     // [4096]
#define WS_WKV  711168     // [4096][160]

typedef _Float16 half4_t __attribute__((ext_vector_type(4)));
typedef _Float16 half2_t __attribute__((ext_vector_type(2)));

__device__ __forceinline__ float dot4acc(const float4 w, const float4 v, float a) {
    a = fmaf(w.x, v.x, a);
    a = fmaf(w.y, v.y, a);
    a = fmaf(w.z, v.z, a);
    a = fmaf(w.w, v.w, a);
    return a;
}
__device__ __forceinline__ float wave_max(float v) {
    #pragma unroll
    for (int off = 32; off > 0; off >>= 1) v = fmaxf(v, __shfl_xor(v, off, 64));
    return v;
}
__device__ __forceinline__ float wave_sum(float v) {
    #pragma unroll
    for (int off = 32; off > 0; off >>= 1) v += __shfl_xor(v, off, 64);
    return v;
}

// ---------------- K1: fold weight matrices ----------------
__global__ void setup_kernel(const float* __restrict__ ipw, const float* __restrict__ ipb,
                             const float* __restrict__ ow,  const float* __restrict__ ob,
                             float* __restrict__ ws)
{
    const int g = blockIdx.x * blockDim.x + threadIdx.x;
    const float inv = 0.07905694150420949f;  // 1/sqrt(160)
    if (g < 25600) {
        const int e = g / DD, f = g % DD;
        const float* wk = ipw + DD * DD;
        float a = 0.f;
        for (int d = 0; d < DD; ++d) a = fmaf(wk[d * DD + e], ipw[d * DD + f], a);
        ws[WS_M + g] = a * inv;
    } else if (g < 51200) {
        const int gg = g - 25600;
        const int i = gg / DD, f = gg % DD;
        const float* wv = ipw + 2 * DD * DD;
        float a = 0.f;
        for (int d = 0; d < DD; ++d) a = fmaf(ow[i * DD + d], wv[d * DD + f], a);
        ws[WS_V2 + gg] = a;
    } else if (g < 51360) {
        const int e = g - 51200;
        const float* wk = ipw + DD * DD;
        float a = 0.f;
        for (int d = 0; d < DD; ++d) a = fmaf(wk[d * DD + e], ipb[d], a);
        ws[WS_C + e] = a * inv;
    } else if (g < 51520) {
        const int f = g - 51360;
        float a = 0.f;
        for (int d = 0; d < DD; ++d) a = fmaf(ipw[d * DD + f], ipb[DD + d], a);
        ws[WS_U + f] = a * inv;
    } else if (g < 51680) {
        const int i = g - 51520;
        float a = ob[i];
        for (int d = 0; d < DD; ++d) a = fmaf(ow[i * DD + d], ipb[2 * DD + d], a);
        ws[WS_B2 + i] = a;
    } else if (g == 51680) {
        float a = 0.f;
        for (int d = 0; d < DD; ++d) a = fmaf(ipb[d], ipb[DD + d], a);
        ws[WS_S0] = a * inv;
    }
}

// ---------------- K2: qt = qin @ M^T + C ; sbk = qin.U + s0 ----------------
__global__ __launch_bounds__(256)
void qt_kernel(const float* __restrict__ x,
               const int* __restrict__ tni, const int* __restrict__ tnt,
               const float* __restrict__ te_w, const float* __restrict__ te_b,
               float* __restrict__ ws)
{
    __shared__ __attribute__((aligned(16))) float s_qin[16][164];
    __shared__ int   s_tn[16];
    __shared__ float s_tt[16];
    const int t  = threadIdx.x;
    const int b0 = blockIdx.x * 16;

    if (t < 16) { s_tn[t] = tni[b0 + t]; s_tt[t] = (float)tnt[b0 + t]; }
    __syncthreads();

    {
        const int r = t >> 4, seg = t & 15;
        const float4* src = (const float4*)(x + (long)s_tn[r] * F_DIM + seg * 8);
        const float4 a = src[0], bq = src[1];
        *(float4*)&s_qin[r][seg * 8]     = a;
        *(float4*)&s_qin[r][seg * 8 + 4] = bq;
        const int j2 = seg * 2;
        s_qin[r][F_DIM + j2]     = cosf(s_tt[r] * te_w[j2]     + te_b[j2]);
        s_qin[r][F_DIM + j2 + 1] = cosf(s_tt[r] * te_w[j2 + 1] + te_b[j2 + 1]);
    }
    __syncthreads();

    {
        const int r = t >> 4, seg = t & 15;
        const float* U = ws + WS_U;
        float p = 0.f;
        #pragma unroll
        for (int i = 0; i < 10; ++i) p = fmaf(s_qin[r][seg * 10 + i], U[seg * 10 + i], p);
        #pragma unroll
        for (int off = 1; off < 16; off <<= 1) p += __shfl_xor(p, off, 64);
        if (seg == 0) ws[WS_SBK + b0 + r] = p + ws[WS_S0];
    }

    {
        const int r = t & 15, eg = t >> 4;
        const float* M = ws + WS_M;
        const float* C = ws + WS_C;
        float acc[10];
        #pragma unroll
        for (int j = 0; j < 10; ++j) acc[j] = C[eg * 10 + j];
        for (int f0 = 0; f0 < DD; f0 += 8) {
            const float4 q0 = *(const float4*)&s_qin[r][f0];
            const float4 q1 = *(const float4*)&s_qin[r][f0 + 4];
            #pragma unroll
            for (int j = 0; j < 10; ++j) {
                const float4* mp = (const float4*)(M + (long)(eg * 10 + j) * DD + f0);
                acc[j] = dot4acc(mp[0], q0, acc[j]);
                acc[j] = dot4acc(mp[1], q1, acc[j]);
            }
        }
        float* qt = ws + WS_QT + (long)(b0 + r) * DD + eg * 10;
        #pragma unroll
        for (int j = 0; j < 10; ++j) qt[j] = acc[j];
    }
}

// ---------------- K3: single-gather scores -> softmax -> mask -> wkv --------
// 2 targets/block, 2 waves/target. x rows gathered ONCE (fp32 for scores),
// stashed fp16 in LDS, reused for wkv. ~47 KB LDS -> 3 blocks/CU.
__global__ __launch_bounds__(256, 4)
void attn_kernel(const float* __restrict__ x,
                 const int* __restrict__ neighbor_ids,
                 const int* __restrict__ edge_time,
                 const float* __restrict__ gumbel_u,
                 const float* __restrict__ te_w, const float* __restrict__ te_b,
                 float* __restrict__ ws,
                 float* __restrict__ out_mask)
{
    __shared__ __attribute__((aligned(16))) _Float16 s_xrow[TPB][KK][XR_STRIDE];
    __shared__ __attribute__((aligned(4)))  _Float16 s_te[TPB][KK][TE_STRIDE];
    __shared__ int   s_nid[TPB][KK];
    __shared__ float s_sc[TPB][KK];
    __shared__ float s_aw[TPB][KK];
    __shared__ float s_qte[TPB][TE_DIM];
    __shared__ float s_wp[TPB][2][DD];

    const int tid  = threadIdx.x;
    const int w    = tid >> 6;
    const int lane = tid & 63;
    const int t    = w >> 1;   // target within block
    const int h    = w & 1;    // k-range half
    const long b   = (long)blockIdx.x * TPB + t;

    // ---- P0: meta + te table (wave (t,h) owns k in [32h, 32h+32)) ----
    {
        if (lane < 32) s_nid[t][32 * h + lane] = neighbor_ids[b * KK + 32 * h + lane];
        const int kl   = 32 * h + (lane >> 1);
        const int side = lane & 1;
        const float etv = (float)edge_time[b * KK + kl];
        #pragma unroll
        for (int q = 0; q < 8; ++q) {
            const int jj = 8 * side + q;
            union { _Float16 hh[2]; unsigned u; } pk;
            pk.hh[0] = (_Float16)cosf(etv * te_w[2 * jj]     + te_b[2 * jj]);
            pk.hh[1] = (_Float16)cosf(etv * te_w[2 * jj + 1] + te_b[2 * jj + 1]);
            *(unsigned*)&s_te[t][kl][2 * jj] = pk.u;
        }
        if (h == 0 && lane < TE_DIM) s_qte[t][lane] = ws[WS_QT + b * DD + F_DIM + lane];
    }

    // qt fragment (halves load identical addresses -> requests merge)
    const int fl = lane & 31, h2 = lane >> 5;
    const float4 qf = *(const float4*)(ws + WS_QT + b * DD + 4 * fl);
    const float sbk = ws[WS_SBK + b];

    // ---- P1: score gather (single x pass) + fp16 stash ----
    #pragma unroll 4
    for (int i = 0; i < 16; ++i) {
        const int k  = 32 * h + 2 * i + h2;
        const int nk = s_nid[t][k];
        const float4 xv = *(const float4*)(x + (long)nk * F_DIM + 4 * fl);
        half4_t hv;
        hv.x = (_Float16)xv.x; hv.y = (_Float16)xv.y;
        hv.z = (_Float16)xv.z; hv.w = (_Float16)xv.w;
        *(half4_t*)&s_xrow[t][k][4 * fl] = hv;
        float p = dot4acc(xv, qf, 0.f);
        p += __shfl_xor(p, 16, 64);
        p += __shfl_xor(p, 8, 64);
        p += __shfl_xor(p, 4, 64);
        p += __shfl_xor(p, 2, 64);
        p += __shfl_xor(p, 1, 64);
        if (fl == 0) s_sc[t][k] = p;
    }
    __syncthreads();

    // ---- P2: softmax over k = lane (both waves of target, redundant) ----
    float aw;
    {
        float tedot = 0.f;
        #pragma unroll
        for (int jj = 0; jj < 16; ++jj) {
            union { _Float16 hh[2]; unsigned u; } pk;
            pk.u = *(const unsigned*)&s_te[t][lane][2 * jj];
            tedot = fmaf(s_qte[t][2 * jj],     (float)pk.hh[0], tedot);
            tedot = fmaf(s_qte[t][2 * jj + 1], (float)pk.hh[1], tedot);
        }
        const float sc = s_sc[t][lane] + tedot + sbk;
        const float m = wave_max(sc);
        const float e = expf(sc - m);
        const float l = wave_sum(e);
        aw = e / l;
        if (h == 0) s_aw[t][lane] = aw;
    }

    // ---- P3: gumbel mask (h==0 wave; depends only on own aw) ----
    if (h == 0) {
        const float u = gumbel_u[b * KK + lane];
        const float g = -logf(-logf(u + 1e-10f) + 1e-10f);
        const float z = aw + g;  // TAU = 1.0
        const float m = wave_max(z);
        const float e = expf(z - m);
        const float l = wave_sum(e);
        out_mask[b * KK + lane] = (e / l > 0.2f) ? 1.0f : 0.0f;
    }
    __syncthreads();

    // ---- P4: wkv partials from LDS (wave (t,h) covers its k half) ----
    {
        float ax = 0.f, ay = 0.f, at = 0.f;
        const int lte = lane & 31;
        #pragma unroll 8
        for (int kk = 0; kk < 32; ++kk) {
            const int k = 32 * h + kk;
            const float wgt = s_aw[t][k];
            const half2_t hp = *(const half2_t*)&s_xrow[t][k][2 * lane];
            ax = fmaf(wgt, (float)hp.x, ax);
            ay = fmaf(wgt, (float)hp.y, ay);
            at = fmaf(wgt, (float)s_te[t][k][lte], at);
        }
        s_wp[t][h][2 * lane]     = ax;
        s_wp[t][h][2 * lane + 1] = ay;
        if (lane < TE_DIM) s_wp[t][h][F_DIM + lane] = at;
    }
    __syncthreads();

    // ---- P5: combine halves, write wkv (h==0 wave per target) ----
    if (h == 0) {
        float* wkv = ws + WS_WKV + b * DD;
        wkv[lane]      = s_wp[t][0][lane]      + s_wp[t][1][lane];
        wkv[lane + 64] = s_wp[t][0][lane + 64] + s_wp[t][1][lane + 64];
        if (lane < 32)
            wkv[lane + 128] = s_wp[t][0][lane + 128] + s_wp[t][1][lane + 128];
    }
}

// ---------------- K4: ao = wkv @ V2^T + B2 ; epilogue ----------------
__global__ __launch_bounds__(256)
void ao_kernel(const float* __restrict__ edge_weight,
               const float* __restrict__ mlp_w, const float* __restrict__ mlp_b,
               float* __restrict__ ws,
               float* __restrict__ out_ao, float* __restrict__ out_new)
{
    __shared__ __attribute__((aligned(16))) float s_v[16][164];
    __shared__ __attribute__((aligned(16))) float s_ao[16][164];
    __shared__ float s_base[16];
    const int t  = threadIdx.x;
    const int b0 = blockIdx.x * 16;

    #pragma unroll
    for (int c = 0; c < 10; ++c) {
        const int idx = t + 256 * c;
        s_v[idx / DD][idx % DD] = ws[WS_WKV + (long)b0 * DD + idx];
    }
    __syncthreads();

    {
        const int r = t & 15, eg = t >> 4;
        const float* V2 = ws + WS_V2;
        const float* B2 = ws + WS_B2;
        float acc[10];
        #pragma unroll
        for (int j = 0; j < 10; ++j) acc[j] = B2[eg * 10 + j];
        for (int f0 = 0; f0 < DD; f0 += 8) {
            const float4 q0 = *(const float4*)&s_v[r][f0];
            const float4 q1 = *(const float4*)&s_v[r][f0 + 4];
            #pragma unroll
            for (int j = 0; j < 10; ++j) {
                const float4* mp = (const float4*)(V2 + (long)(eg * 10 + j) * DD + f0);
                acc[j] = dot4acc(mp[0], q0, acc[j]);
                acc[j] = dot4acc(mp[1], q1, acc[j]);
            }
        }
        #pragma unroll
        for (int j = 0; j < 10; ++j) s_ao[r][eg * 10 + j] = acc[j];
    }
    __syncthreads();

    {
        const int r = t >> 4, seg = t & 15;
        float p = 0.f;
        #pragma unroll
        for (int i = 0; i < 10; ++i) p = fmaf(s_ao[r][seg * 10 + i], mlp_w[seg * 10 + i], p);
        #pragma unroll
        for (int off = 1; off < 16; off <<= 1) p += __shfl_xor(p, off, 64);
        if (seg == 0) s_base[r] = p + mlp_b[0];
    }
    __syncthreads();

    #pragma unroll
    for (int c = 0; c < 10; ++c) {
        const int idx = t + 256 * c;
        out_ao[(long)b0 * DD + idx] = s_ao[idx / DD][idx % DD];
    }
    #pragma unroll
    for (int c = 0; c < 4; ++c) {
        const int idx = t + 256 * c;
        const int r = idx >> 6, kx = idx & 63;
        const float ew  = edge_weight[(long)(b0 + r) * KK + kx];
        const float val = fmaf(ew, mlp_w[DD], s_base[r]);
        out_new[(long)(b0 + r) * KK + kx] = (val >= 0.f) ? val : 0.01f * val;
    }
}

extern "C" void kernel_launch(void* const* d_in, const int* in_sizes, int n_in,
                              void* d_out, int out_size, void* d_ws, size_t ws_size,
                              hipStream_t stream) {
    const float* x   = (const float*)d_in[0];
    const int*   tni = (const int*)d_in[1];
    const int*   tnt = (const int*)d_in[2];
    const int*   nid = (const int*)d_in[3];
    const int*   et  = (const int*)d_in[4];
    const float* ew  = (const float*)d_in[5];
    const float* gu  = (const float*)d_in[6];
    const float* tew = (const float*)d_in[7];
    const float* teb = (const float*)d_in[8];
    const float* ipw = (const float*)d_in[9];
    const float* ipb = (const float*)d_in[10];
    const float* ow  = (const float*)d_in[11];
    const float* ob  = (const float*)d_in[12];
    const float* mw  = (const float*)d_in[13];
    const float* mb  = (const float*)d_in[14];

    float* wsf = (float*)d_ws;

    float* out      = (float*)d_out;
    float* out_ao   = out;
    float* out_new  = out + (long)NB * DD;
    float* out_mask = out + (long)NB * DD + (long)NB * KK;

    setup_kernel<<<(WS_WTOT + 255) / 256, 256, 0, stream>>>(ipw, ipb, ow, ob, wsf);
    qt_kernel<<<NB / 16, 256, 0, stream>>>(x, tni, tnt, tew, teb, wsf);
    attn_kernel<<<NB / TPB, 256, 0, stream>>>(x, nid, et, gu, tew, teb, wsf, out_mask);
    ao_kernel<<<NB / 16, 256, 0, stream>>>(ew, mw, mb, wsf, out_ao, out_new);
}

// Round 6
// 192.904 us; speedup vs baseline: 1.0681x; 1.0681x over previous
//
#include <hip/hip_runtime.h>

#define F_DIM 128
#define TE_DIM 32
#define DD 160
#define NB 4096
#define KK 64
#define TPB 2          // targets per attn block (2 waves each)
#define TE_STRIDE 34   // halves; 68 B row: 17-dword stride -> <=2-way (free)

// ws layout (float offsets). Total 1366528 floats = 5.47 MB of d_ws.
#define WS_M    0          // [160][160]  (Wk^T Wq) / sqrt(160)
#define WS_V2   25600      // [160][160]  out_w @ Wv
#define WS_C    51200      // [160]       (Wk^T bq) / sqrt(160)
#define WS_U    51360      // [160]       (Wq^T bk) / sqrt(160)
#define WS_B2   51520      // [160]       out_w @ bv + out_b
#define WS_S0   51680      // [1]         (bq . bk) / sqrt(160)
#define WS_WTOT 51681
#define WS_QT   51712      // [4096][160] q_tilde
#define WS_SBK  707072     // [4096]
#define WS_WKV  711168     // [4096][160]

typedef _Float16 half4_t __attribute__((ext_vector_type(4)));

__device__ __forceinline__ float dot4acc(const float4 w, const float4 v, float a) {
    a = fmaf(w.x, v.x, a);
    a = fmaf(w.y, v.y, a);
    a = fmaf(w.z, v.z, a);
    a = fmaf(w.w, v.w, a);
    return a;
}
__device__ __forceinline__ float wave_max(float v) {
    #pragma unroll
    for (int off = 32; off > 0; off >>= 1) v = fmaxf(v, __shfl_xor(v, off, 64));
    return v;
}
__device__ __forceinline__ float wave_sum(float v) {
    #pragma unroll
    for (int off = 32; off > 0; off >>= 1) v += __shfl_xor(v, off, 64);
    return v;
}

// ---------------- K1: fold weight matrices ----------------
__global__ void setup_kernel(const float* __restrict__ ipw, const float* __restrict__ ipb,
                             const float* __restrict__ ow,  const float* __restrict__ ob,
                             float* __restrict__ ws)
{
    const int g = blockIdx.x * blockDim.x + threadIdx.x;
    const float inv = 0.07905694150420949f;  // 1/sqrt(160)
    if (g < 25600) {
        const int e = g / DD, f = g % DD;
        const float* wk = ipw + DD * DD;
        float a = 0.f;
        for (int d = 0; d < DD; ++d) a = fmaf(wk[d * DD + e], ipw[d * DD + f], a);
        ws[WS_M + g] = a * inv;
    } else if (g < 51200) {
        const int gg = g - 25600;
        const int i = gg / DD, f = gg % DD;
        const float* wv = ipw + 2 * DD * DD;
        float a = 0.f;
        for (int d = 0; d < DD; ++d) a = fmaf(ow[i * DD + d], wv[d * DD + f], a);
        ws[WS_V2 + gg] = a;
    } else if (g < 51360) {
        const int e = g - 51200;
        const float* wk = ipw + DD * DD;
        float a = 0.f;
        for (int d = 0; d < DD; ++d) a = fmaf(wk[d * DD + e], ipb[d], a);
        ws[WS_C + e] = a * inv;
    } else if (g < 51520) {
        const int f = g - 51360;
        float a = 0.f;
        for (int d = 0; d < DD; ++d) a = fmaf(ipw[d * DD + f], ipb[DD + d], a);
        ws[WS_U + f] = a * inv;
    } else if (g < 51680) {
        const int i = g - 51520;
        float a = ob[i];
        for (int d = 0; d < DD; ++d) a = fmaf(ow[i * DD + d], ipb[2 * DD + d], a);
        ws[WS_B2 + i] = a;
    } else if (g == 51680) {
        float a = 0.f;
        for (int d = 0; d < DD; ++d) a = fmaf(ipb[d], ipb[DD + d], a);
        ws[WS_S0] = a * inv;
    }
}

// ---------------- K2: qt = qin @ M^T + C ; sbk = qin.U + s0 ----------------
__global__ __launch_bounds__(256)
void qt_kernel(const float* __restrict__ x,
               const int* __restrict__ tni, const int* __restrict__ tnt,
               const float* __restrict__ te_w, const float* __restrict__ te_b,
               float* __restrict__ ws)
{
    __shared__ __attribute__((aligned(16))) float s_qin[16][164];
    __shared__ int   s_tn[16];
    __shared__ float s_tt[16];
    const int t  = threadIdx.x;
    const int b0 = blockIdx.x * 16;

    if (t < 16) { s_tn[t] = tni[b0 + t]; s_tt[t] = (float)tnt[b0 + t]; }
    __syncthreads();

    {
        const int r = t >> 4, seg = t & 15;
        const float4* src = (const float4*)(x + (long)s_tn[r] * F_DIM + seg * 8);
        const float4 a = src[0], bq = src[1];
        *(float4*)&s_qin[r][seg * 8]     = a;
        *(float4*)&s_qin[r][seg * 8 + 4] = bq;
        const int j2 = seg * 2;
        s_qin[r][F_DIM + j2]     = cosf(s_tt[r] * te_w[j2]     + te_b[j2]);
        s_qin[r][F_DIM + j2 + 1] = cosf(s_tt[r] * te_w[j2 + 1] + te_b[j2 + 1]);
    }
    __syncthreads();

    {
        const int r = t >> 4, seg = t & 15;
        const float* U = ws + WS_U;
        float p = 0.f;
        #pragma unroll
        for (int i = 0; i < 10; ++i) p = fmaf(s_qin[r][seg * 10 + i], U[seg * 10 + i], p);
        #pragma unroll
        for (int off = 1; off < 16; off <<= 1) p += __shfl_xor(p, off, 64);
        if (seg == 0) ws[WS_SBK + b0 + r] = p + ws[WS_S0];
    }

    {
        const int r = t & 15, eg = t >> 4;
        const float* M = ws + WS_M;
        const float* C = ws + WS_C;
        float acc[10];
        #pragma unroll
        for (int j = 0; j < 10; ++j) acc[j] = C[eg * 10 + j];
        for (int f0 = 0; f0 < DD; f0 += 8) {
            const float4 q0 = *(const float4*)&s_qin[r][f0];
            const float4 q1 = *(const float4*)&s_qin[r][f0 + 4];
            #pragma unroll
            for (int j = 0; j < 10; ++j) {
                const float4* mp = (const float4*)(M + (long)(eg * 10 + j) * DD + f0);
                acc[j] = dot4acc(mp[0], q0, acc[j]);
                acc[j] = dot4acc(mp[1], q1, acc[j]);
            }
        }
        float* qt = ws + WS_QT + (long)(b0 + r) * DD + eg * 10;
        #pragma unroll
        for (int j = 0; j < 10; ++j) qt[j] = acc[j];
    }
}

// ---------------- K3: single-gather attn, register x-stash ------------------
// 2 targets/block, 2 waves/target. Each lane gathers 16 float4 x-fragments
// (all in flight), keeps them packed fp16 in 32 VGPRs, reuses for wkv.
// LDS ~13 KB; VGPR-bound ~4 blocks/CU.
__global__ __launch_bounds__(256, 4)
void attn_kernel(const float* __restrict__ x,
                 const int* __restrict__ neighbor_ids,
                 const int* __restrict__ edge_time,
                 const float* __restrict__ gumbel_u,
                 const float* __restrict__ te_w, const float* __restrict__ te_b,
                 float* __restrict__ ws,
                 float* __restrict__ out_mask)
{
    __shared__ __attribute__((aligned(4))) _Float16 s_te[TPB][KK][TE_STRIDE];
    __shared__ int   s_nid[TPB][KK];
    __shared__ float s_sc[TPB][KK];
    __shared__ float s_aw[TPB][KK];
    __shared__ float s_qte[TPB][TE_DIM];
    __shared__ __attribute__((aligned(16))) float s_wp[TPB][2][DD];

    const int tid  = threadIdx.x;
    const int w    = tid >> 6;
    const int lane = tid & 63;
    const int t    = w >> 1;   // target within block
    const int h    = w & 1;    // k-range half
    const long b   = (long)blockIdx.x * TPB + t;

    // ---- P0: meta + te table (wave (t,h) owns k in [32h, 32h+32)) ----
    {
        if (lane < 32) s_nid[t][32 * h + lane] = neighbor_ids[b * KK + 32 * h + lane];
        const int kl   = 32 * h + (lane >> 1);
        const int side = lane & 1;
        const float etv = (float)edge_time[b * KK + kl];
        #pragma unroll
        for (int q = 0; q < 8; ++q) {
            const int jj = 8 * side + q;
            union { _Float16 hh[2]; unsigned u; } pk;
            pk.hh[0] = (_Float16)cosf(etv * te_w[2 * jj]     + te_b[2 * jj]);
            pk.hh[1] = (_Float16)cosf(etv * te_w[2 * jj + 1] + te_b[2 * jj + 1]);
            *(unsigned*)&s_te[t][kl][2 * jj] = pk.u;
        }
        if (h == 0 && lane < TE_DIM) s_qte[t][lane] = ws[WS_QT + b * DD + F_DIM + lane];
    }

    // qt fragment (h2 halves load identical addresses -> requests merge)
    const int fl = lane & 31, h2 = lane >> 5;
    const float4 qf = *(const float4*)(ws + WS_QT + b * DD + 4 * fl);
    const float sbk = ws[WS_SBK + b];

    // ---- P1: score gather (single x pass), fp16 register stash ----
    half4_t rx[16];
    #pragma unroll
    for (int i = 0; i < 16; ++i) {
        const int k  = 32 * h + 2 * i + h2;
        const int nk = s_nid[t][k];
        const float4 xv = *(const float4*)(x + (long)nk * F_DIM + 4 * fl);
        half4_t hv;
        hv.x = (_Float16)xv.x; hv.y = (_Float16)xv.y;
        hv.z = (_Float16)xv.z; hv.w = (_Float16)xv.w;
        rx[i] = hv;
        float p = dot4acc(xv, qf, 0.f);
        p += __shfl_xor(p, 16, 64);
        p += __shfl_xor(p, 8, 64);
        p += __shfl_xor(p, 4, 64);
        p += __shfl_xor(p, 2, 64);
        p += __shfl_xor(p, 1, 64);
        if (fl == 0) s_sc[t][k] = p;
    }
    __syncthreads();

    // ---- P2: softmax over k = lane (both waves redundantly; benign
    //      identical-value WAW on s_aw -> wave-coherent reads, no barrier) ----
    float aw;
    {
        float tedot = 0.f;
        #pragma unroll
        for (int jj = 0; jj < 16; ++jj) {
            union { _Float16 hh[2]; unsigned u; } pk;
            pk.u = *(const unsigned*)&s_te[t][lane][2 * jj];
            tedot = fmaf(s_qte[t][2 * jj],     (float)pk.hh[0], tedot);
            tedot = fmaf(s_qte[t][2 * jj + 1], (float)pk.hh[1], tedot);
        }
        const float sc = s_sc[t][lane] + tedot + sbk;
        const float m = wave_max(sc);
        const float e = expf(sc - m);
        const float l = wave_sum(e);
        aw = e / l;
        s_aw[t][lane] = aw;
    }

    // ---- P3: gumbel mask (h==0 wave; own-register aw) ----
    if (h == 0) {
        const float u = gumbel_u[b * KK + lane];
        const float g = -logf(-logf(u + 1e-10f) + 1e-10f);
        const float z = aw + g;  // TAU = 1.0
        const float m = wave_max(z);
        const float e = expf(z - m);
        const float l = wave_sum(e);
        out_mask[b * KK + lane] = (e / l > 0.2f) ? 1.0f : 0.0f;
    }

    // ---- P4: wkv from registers ----
    {
        float ax = 0.f, ay = 0.f, az = 0.f, aww = 0.f, at = 0.f;
        #pragma unroll
        for (int i = 0; i < 16; ++i) {
            const int k = 32 * h + 2 * i + h2;
            const float wgt = s_aw[t][k];
            const half4_t hv = rx[i];
            ax  = fmaf(wgt, (float)hv.x, ax);
            ay  = fmaf(wgt, (float)hv.y, ay);
            az  = fmaf(wgt, (float)hv.z, az);
            aww = fmaf(wgt, (float)hv.w, aww);
        }
        const int lte = lane & 31;
        #pragma unroll 8
        for (int kk = 0; kk < 32; ++kk) {
            const int k = 32 * h + kk;
            at = fmaf(s_aw[t][k], (float)s_te[t][k][lte], at);
        }
        // fold h2 halves (k parity) together
        ax  += __shfl_xor(ax, 32, 64);
        ay  += __shfl_xor(ay, 32, 64);
        az  += __shfl_xor(az, 32, 64);
        aww += __shfl_xor(aww, 32, 64);
        if (h2 == 0) {
            float4 v = make_float4(ax, ay, az, aww);
            *(float4*)&s_wp[t][h][4 * fl] = v;
        }
        if (lane < TE_DIM) s_wp[t][h][F_DIM + lane] = at;
    }
    __syncthreads();

    // ---- P5: combine wave halves, write wkv (h==0 wave per target) ----
    if (h == 0) {
        float* wkv = ws + WS_WKV + b * DD;
        wkv[lane]      = s_wp[t][0][lane]      + s_wp[t][1][lane];
        wkv[lane + 64] = s_wp[t][0][lane + 64] + s_wp[t][1][lane + 64];
        if (lane < 32)
            wkv[lane + 128] = s_wp[t][0][lane + 128] + s_wp[t][1][lane + 128];
    }
}

// ---------------- K4: ao = wkv @ V2^T + B2 ; epilogue ----------------
__global__ __launch_bounds__(256)
void ao_kernel(const float* __restrict__ edge_weight,
               const float* __restrict__ mlp_w, const float* __restrict__ mlp_b,
               float* __restrict__ ws,
               float* __restrict__ out_ao, float* __restrict__ out_new)
{
    __shared__ __attribute__((aligned(16))) float s_v[16][164];
    __shared__ __attribute__((aligned(16))) float s_ao[16][164];
    __shared__ float s_base[16];
    const int t  = threadIdx.x;
    const int b0 = blockIdx.x * 16;

    #pragma unroll
    for (int c = 0; c < 10; ++c) {
        const int idx = t + 256 * c;
        s_v[idx / DD][idx % DD] = ws[WS_WKV + (long)b0 * DD + idx];
    }
    __syncthreads();

    {
        const int r = t & 15, eg = t >> 4;
        const float* V2 = ws + WS_V2;
        const float* B2 = ws + WS_B2;
        float acc[10];
        #pragma unroll
        for (int j = 0; j < 10; ++j) acc[j] = B2[eg * 10 + j];
        for (int f0 = 0; f0 < DD; f0 += 8) {
            const float4 q0 = *(const float4*)&s_v[r][f0];
            const float4 q1 = *(const float4*)&s_v[r][f0 + 4];
            #pragma unroll
            for (int j = 0; j < 10; ++j) {
                const float4* mp = (const float4*)(V2 + (long)(eg * 10 + j) * DD + f0);
                acc[j] = dot4acc(mp[0], q0, acc[j]);
                acc[j] = dot4acc(mp[1], q1, acc[j]);
            }
        }
        #pragma unroll
        for (int j = 0; j < 10; ++j) s_ao[r][eg * 10 + j] = acc[j];
    }
    __syncthreads();

    {
        const int r = t >> 4, seg = t & 15;
        float p = 0.f;
        #pragma unroll
        for (int i = 0; i < 10; ++i) p = fmaf(s_ao[r][seg * 10 + i], mlp_w[seg * 10 + i], p);
        #pragma unroll
        for (int off = 1; off < 16; off <<= 1) p += __shfl_xor(p, off, 64);
        if (seg == 0) s_base[r] = p + mlp_b[0];
    }
    __syncthreads();

    #pragma unroll
    for (int c = 0; c < 10; ++c) {
        const int idx = t + 256 * c;
        out_ao[(long)b0 * DD + idx] = s_ao[idx / DD][idx % DD];
    }
    #pragma unroll
    for (int c = 0; c < 4; ++c) {
        const int idx = t + 256 * c;
        const int r = idx >> 6, kx = idx & 63;
        const float ew  = edge_weight[(long)(b0 + r) * KK + kx];
        const float val = fmaf(ew, mlp_w[DD], s_base[r]);
        out_new[(long)(b0 + r) * KK + kx] = (val >= 0.f) ? val : 0.01f * val;
    }
}

extern "C" void kernel_launch(void* const* d_in, const int* in_sizes, int n_in,
                              void* d_out, int out_size, void* d_ws, size_t ws_size,
                              hipStream_t stream) {
    const float* x   = (const float*)d_in[0];
    const int*   tni = (const int*)d_in[1];
    const int*   tnt = (const int*)d_in[2];
    const int*   nid = (const int*)d_in[3];
    const int*   et  = (const int*)d_in[4];
    const float* ew  = (const float*)d_in[5];
    const float* gu  = (const float*)d_in[6];
    const float* tew = (const float*)d_in[7];
    const float* teb = (const float*)d_in[8];
    const float* ipw = (const float*)d_in[9];
    const float* ipb = (const float*)d_in[10];
    const float* ow  = (const float*)d_in[11];
    const float* ob  = (const float*)d_in[12];
    const float* mw  = (const float*)d_in[13];
    const float* mb  = (const float*)d_in[14];

    float* wsf = (float*)d_ws;

    float* out      = (float*)d_out;
    float* out_ao   = out;
    float* out_new  = out + (long)NB * DD;
    float* out_mask = out + (long)NB * DD + (long)NB * KK;

    setup_kernel<<<(WS_WTOT + 255) / 256, 256, 0, stream>>>(ipw, ipb, ow, ob, wsf);
    qt_kernel<<<NB / 16, 256, 0, stream>>>(x, tni, tnt, tew, teb, wsf);
    attn_kernel<<<NB / TPB, 256, 0, stream>>>(x, nid, et, gu, tew, teb, wsf, out_mask);
    ao_kernel<<<NB / 16, 256, 0, stream>>>(ew, mw, mb, wsf, out_ao, out_new);
}

// Round 7
// 187.085 us; speedup vs baseline: 1.1013x; 1.0311x over previous
//
#include <hip/hip_runtime.h>

#define F_DIM 128
#define TE_DIM 32
#define DD 160
#define NB 4096
#define KK 64
#define TPB 2          // targets per attn block (2 waves each)
#define TE_STRIDE 34   // halves; 17-dword rows -> <=2-way (free)
#define PT_STRIDE 33   // s_part row stride: 2-way max on write, free

// ws layout (float offsets). Total 1366528 floats = 5.47 MB of d_ws.
#define WS_M    0          // [160][160]  (Wk^T Wq) / sqrt(160)
#define WS_V2   25600      // [160][160]  out_w @ Wv
#define WS_C    51200      // [160]       (Wk^T bq) / sqrt(160)
#define WS_U    51360      // [160]       (Wq^T bk) / sqrt(160)
#define WS_B2   51520      // [160]       out_w @ bv + out_b
#define WS_S0   51680      // [1]         (bq . bk) / sqrt(160)
#define WS_WTOT 51681
#define WS_QT   51712      // [4096][160] q_tilde
#define WS_SBK  707072     // [4096]
#define WS_WKV  711168     // [4096][160]

typedef _Float16 half4_t __attribute__((ext_vector_type(4)));

__device__ __forceinline__ float dot4acc(const float4 w, const float4 v, float a) {
    a = fmaf(w.x, v.x, a);
    a = fmaf(w.y, v.y, a);
    a = fmaf(w.z, v.z, a);
    a = fmaf(w.w, v.w, a);
    return a;
}
__device__ __forceinline__ float wave_max(float v) {
    #pragma unroll
    for (int off = 32; off > 0; off >>= 1) v = fmaxf(v, __shfl_xor(v, off, 64));
    return v;
}
__device__ __forceinline__ float wave_sum(float v) {
    #pragma unroll
    for (int off = 32; off > 0; off >>= 1) v += __shfl_xor(v, off, 64);
    return v;
}

// ---------------- K1: fold weight matrices (4-way ILP in K-loop) ------------
__global__ void setup_kernel(const float* __restrict__ ipw, const float* __restrict__ ipb,
                             const float* __restrict__ ow,  const float* __restrict__ ob,
                             float* __restrict__ ws)
{
    const int g = blockIdx.x * blockDim.x + threadIdx.x;
    const float inv = 0.07905694150420949f;  // 1/sqrt(160)
    if (g < 25600) {
        const int e = g / DD, f = g % DD;
        const float* wk = ipw + DD * DD;
        float a0 = 0.f, a1 = 0.f, a2 = 0.f, a3 = 0.f;
        #pragma unroll 4
        for (int d = 0; d < DD; d += 4) {
            a0 = fmaf(wk[(d + 0) * DD + e], ipw[(d + 0) * DD + f], a0);
            a1 = fmaf(wk[(d + 1) * DD + e], ipw[(d + 1) * DD + f], a1);
            a2 = fmaf(wk[(d + 2) * DD + e], ipw[(d + 2) * DD + f], a2);
            a3 = fmaf(wk[(d + 3) * DD + e], ipw[(d + 3) * DD + f], a3);
        }
        ws[WS_M + g] = ((a0 + a1) + (a2 + a3)) * inv;
    } else if (g < 51200) {
        const int gg = g - 25600;
        const int i = gg / DD, f = gg % DD;
        const float* wv = ipw + 2 * DD * DD;
        float a0 = 0.f, a1 = 0.f, a2 = 0.f, a3 = 0.f;
        #pragma unroll 4
        for (int d = 0; d < DD; d += 4) {
            a0 = fmaf(ow[i * DD + d + 0], wv[(d + 0) * DD + f], a0);
            a1 = fmaf(ow[i * DD + d + 1], wv[(d + 1) * DD + f], a1);
            a2 = fmaf(ow[i * DD + d + 2], wv[(d + 2) * DD + f], a2);
            a3 = fmaf(ow[i * DD + d + 3], wv[(d + 3) * DD + f], a3);
        }
        ws[WS_V2 + gg] = (a0 + a1) + (a2 + a3);
    } else if (g < 51360) {
        const int e = g - 51200;
        const float* wk = ipw + DD * DD;
        float a = 0.f;
        #pragma unroll 4
        for (int d = 0; d < DD; ++d) a = fmaf(wk[d * DD + e], ipb[d], a);
        ws[WS_C + e] = a * inv;
    } else if (g < 51520) {
        const int f = g - 51360;
        float a = 0.f;
        #pragma unroll 4
        for (int d = 0; d < DD; ++d) a = fmaf(ipw[d * DD + f], ipb[DD + d], a);
        ws[WS_U + f] = a * inv;
    } else if (g < 51680) {
        const int i = g - 51520;
        float a = ob[i];
        #pragma unroll 4
        for (int d = 0; d < DD; ++d) a = fmaf(ow[i * DD + d], ipb[2 * DD + d], a);
        ws[WS_B2 + i] = a;
    } else if (g == 51680) {
        float a = 0.f;
        for (int d = 0; d < DD; ++d) a = fmaf(ipb[d], ipb[DD + d], a);
        ws[WS_S0] = a * inv;
    }
}

// ---------------- K2: qt = qin @ M^T + C ; sbk = qin.U + s0 ----------------
__global__ __launch_bounds__(256)
void qt_kernel(const float* __restrict__ x,
               const int* __restrict__ tni, const int* __restrict__ tnt,
               const float* __restrict__ te_w, const float* __restrict__ te_b,
               float* __restrict__ ws)
{
    __shared__ __attribute__((aligned(16))) float s_qin[16][164];
    __shared__ int   s_tn[16];
    __shared__ float s_tt[16];
    const int t  = threadIdx.x;
    const int b0 = blockIdx.x * 16;

    if (t < 16) { s_tn[t] = tni[b0 + t]; s_tt[t] = (float)tnt[b0 + t]; }
    __syncthreads();

    {
        const int r = t >> 4, seg = t & 15;
        const float4* src = (const float4*)(x + (long)s_tn[r] * F_DIM + seg * 8);
        const float4 a = src[0], bq = src[1];
        *(float4*)&s_qin[r][seg * 8]     = a;
        *(float4*)&s_qin[r][seg * 8 + 4] = bq;
        const int j2 = seg * 2;
        s_qin[r][F_DIM + j2]     = cosf(s_tt[r] * te_w[j2]     + te_b[j2]);
        s_qin[r][F_DIM + j2 + 1] = cosf(s_tt[r] * te_w[j2 + 1] + te_b[j2 + 1]);
    }
    __syncthreads();

    {
        const int r = t >> 4, seg = t & 15;
        const float* U = ws + WS_U;
        float p = 0.f;
        #pragma unroll
        for (int i = 0; i < 10; ++i) p = fmaf(s_qin[r][seg * 10 + i], U[seg * 10 + i], p);
        #pragma unroll
        for (int off = 1; off < 16; off <<= 1) p += __shfl_xor(p, off, 64);
        if (seg == 0) ws[WS_SBK + b0 + r] = p + ws[WS_S0];
    }

    {
        const int r = t & 15, eg = t >> 4;
        const float* M = ws + WS_M;
        const float* C = ws + WS_C;
        float acc[10];
        #pragma unroll
        for (int j = 0; j < 10; ++j) acc[j] = C[eg * 10 + j];
        for (int f0 = 0; f0 < DD; f0 += 8) {
            const float4 q0 = *(const float4*)&s_qin[r][f0];
            const float4 q1 = *(const float4*)&s_qin[r][f0 + 4];
            #pragma unroll
            for (int j = 0; j < 10; ++j) {
                const float4* mp = (const float4*)(M + (long)(eg * 10 + j) * DD + f0);
                acc[j] = dot4acc(mp[0], q0, acc[j]);
                acc[j] = dot4acc(mp[1], q1, acc[j]);
            }
        }
        float* qt = ws + WS_QT + (long)(b0 + r) * DD + eg * 10;
        #pragma unroll
        for (int j = 0; j < 10; ++j) qt[j] = acc[j];
    }
}

// ---------------- K3: single-gather attn, register x-stash,
//                  LDS-transpose score reduction (no shuffle chains) ---------
__global__ __launch_bounds__(256, 2)
void attn_kernel(const float* __restrict__ x,
                 const int* __restrict__ neighbor_ids,
                 const int* __restrict__ edge_time,
                 const float* __restrict__ gumbel_u,
                 const float* __restrict__ te_w, const float* __restrict__ te_b,
                 float* __restrict__ ws,
                 float* __restrict__ out_mask)
{
    __shared__ __attribute__((aligned(16))) float s_part[TPB][KK][PT_STRIDE];
    __shared__ __attribute__((aligned(4)))  _Float16 s_te[TPB][KK][TE_STRIDE];
    __shared__ int   s_nid[TPB][KK];
    __shared__ float s_aw[TPB][KK];
    __shared__ float s_qte[TPB][TE_DIM];
    __shared__ __attribute__((aligned(16))) float s_wp[TPB][2][DD];

    const int tid  = threadIdx.x;
    const int w    = tid >> 6;
    const int lane = tid & 63;
    const int t    = w >> 1;   // target within block
    const int h    = w & 1;    // k-range half
    const long b   = (long)blockIdx.x * TPB + t;

    // ---- P0: meta + te table (wave (t,h) owns k in [32h, 32h+32)) ----
    {
        if (lane < 32) s_nid[t][32 * h + lane] = neighbor_ids[b * KK + 32 * h + lane];
        const int kl   = 32 * h + (lane >> 1);
        const int side = lane & 1;
        const float etv = (float)edge_time[b * KK + kl];
        #pragma unroll
        for (int q = 0; q < 8; ++q) {
            const int jj = 8 * side + q;
            union { _Float16 hh[2]; unsigned u; } pk;
            pk.hh[0] = (_Float16)cosf(etv * te_w[2 * jj]     + te_b[2 * jj]);
            pk.hh[1] = (_Float16)cosf(etv * te_w[2 * jj + 1] + te_b[2 * jj + 1]);
            *(unsigned*)&s_te[t][kl][2 * jj] = pk.u;
        }
        if (h == 0 && lane < TE_DIM) s_qte[t][lane] = ws[WS_QT + b * DD + F_DIM + lane];
    }

    // qt fragment (h2 halves load identical addresses -> requests merge)
    const int fl = lane & 31, h2 = lane >> 5;
    const float4 qf = *(const float4*)(ws + WS_QT + b * DD + 4 * fl);
    const float sbk = ws[WS_SBK + b];

    // ---- P1: score gather (single x pass), fp16 register stash.
    //      No cross-lane ops in loop: partial -> LDS, loads fully pipeline. ----
    half4_t rx[16];
    #pragma unroll
    for (int i = 0; i < 16; ++i) {
        const int k  = 32 * h + 2 * i + h2;
        const int nk = s_nid[t][k];
        const float4 xv = *(const float4*)(x + (long)nk * F_DIM + 4 * fl);
        half4_t hv;
        hv.x = (_Float16)xv.x; hv.y = (_Float16)xv.y;
        hv.z = (_Float16)xv.z; hv.w = (_Float16)xv.w;
        rx[i] = hv;
        s_part[t][k][fl] = dot4acc(xv, qf, 0.f);
    }
    __syncthreads();

    // ---- P2: transpose-reduce + softmax over k = lane (both waves
    //      redundantly; benign identical-value WAW on s_aw) ----
    float aw;
    {
        const float4* pr = (const float4*)s_part[t][lane];
        float4 sa = pr[0];
        #pragma unroll
        for (int c = 1; c < 8; ++c) {
            const float4 pv = pr[c];
            sa.x += pv.x; sa.y += pv.y; sa.z += pv.z; sa.w += pv.w;
        }
        float tedot = 0.f;
        #pragma unroll
        for (int jj = 0; jj < 16; ++jj) {
            union { _Float16 hh[2]; unsigned u; } pk;
            pk.u = *(const unsigned*)&s_te[t][lane][2 * jj];
            tedot = fmaf(s_qte[t][2 * jj],     (float)pk.hh[0], tedot);
            tedot = fmaf(s_qte[t][2 * jj + 1], (float)pk.hh[1], tedot);
        }
        const float sc = ((sa.x + sa.y) + (sa.z + sa.w)) + tedot + sbk;
        const float m = wave_max(sc);
        const float e = expf(sc - m);
        const float l = wave_sum(e);
        aw = e / l;
        s_aw[t][lane] = aw;
    }

    // ---- P3: gumbel mask (h==0 wave; own-register aw) ----
    if (h == 0) {
        const float u = gumbel_u[b * KK + lane];
        const float g = -logf(-logf(u + 1e-10f) + 1e-10f);
        const float z = aw + g;  // TAU = 1.0
        const float m = wave_max(z);
        const float e = expf(z - m);
        const float l = wave_sum(e);
        out_mask[b * KK + lane] = (e / l > 0.2f) ? 1.0f : 0.0f;
    }

    // ---- P4: wkv from registers ----
    {
        float ax = 0.f, ay = 0.f, az = 0.f, aww = 0.f, at = 0.f;
        #pragma unroll
        for (int i = 0; i < 16; ++i) {
            const int k = 32 * h + 2 * i + h2;
            const float wgt = s_aw[t][k];
            const half4_t hv = rx[i];
            ax  = fmaf(wgt, (float)hv.x, ax);
            ay  = fmaf(wgt, (float)hv.y, ay);
            az  = fmaf(wgt, (float)hv.z, az);
            aww = fmaf(wgt, (float)hv.w, aww);
        }
        const int lte = lane & 31;
        #pragma unroll 8
        for (int kk = 0; kk < 32; ++kk) {
            const int k = 32 * h + kk;
            at = fmaf(s_aw[t][k], (float)s_te[t][k][lte], at);
        }
        // fold h2 halves (k parity) together
        ax  += __shfl_xor(ax, 32, 64);
        ay  += __shfl_xor(ay, 32, 64);
        az  += __shfl_xor(az, 32, 64);
        aww += __shfl_xor(aww, 32, 64);
        if (h2 == 0) {
            float4 v = make_float4(ax, ay, az, aww);
            *(float4*)&s_wp[t][h][4 * fl] = v;
        }
        if (lane < TE_DIM) s_wp[t][h][F_DIM + lane] = at;
    }
    __syncthreads();

    // ---- P5: combine wave halves, write wkv (h==0 wave per target) ----
    if (h == 0) {
        float* wkv = ws + WS_WKV + b * DD;
        wkv[lane]      = s_wp[t][0][lane]      + s_wp[t][1][lane];
        wkv[lane + 64] = s_wp[t][0][lane + 64] + s_wp[t][1][lane + 64];
        if (lane < 32)
            wkv[lane + 128] = s_wp[t][0][lane + 128] + s_wp[t][1][lane + 128];
    }
}

// ---------------- K4: ao = wkv @ V2^T + B2 ; epilogue ----------------
__global__ __launch_bounds__(256)
void ao_kernel(const float* __restrict__ edge_weight,
               const float* __restrict__ mlp_w, const float* __restrict__ mlp_b,
               float* __restrict__ ws,
               float* __restrict__ out_ao, float* __restrict__ out_new)
{
    __shared__ __attribute__((aligned(16))) float s_v[16][164];
    __shared__ __attribute__((aligned(16))) float s_ao[16][164];
    __shared__ float s_base[16];
    const int t  = threadIdx.x;
    const int b0 = blockIdx.x * 16;

    #pragma unroll
    for (int c = 0; c < 10; ++c) {
        const int idx = t + 256 * c;
        s_v[idx / DD][idx % DD] = ws[WS_WKV + (long)b0 * DD + idx];
    }
    __syncthreads();

    {
        const int r = t & 15, eg = t >> 4;
        const float* V2 = ws + WS_V2;
        const float* B2 = ws + WS_B2;
        float acc[10];
        #pragma unroll
        for (int j = 0; j < 10; ++j) acc[j] = B2[eg * 10 + j];
        for (int f0 = 0; f0 < DD; f0 += 8) {
            const float4 q0 = *(const float4*)&s_v[r][f0];
            const float4 q1 = *(const float4*)&s_v[r][f0 + 4];
            #pragma unroll
            for (int j = 0; j < 10; ++j) {
                const float4* mp = (const float4*)(V2 + (long)(eg * 10 + j) * DD + f0);
                acc[j] = dot4acc(mp[0], q0, acc[j]);
                acc[j] = dot4acc(mp[1], q1, acc[j]);
            }
        }
        #pragma unroll
        for (int j = 0; j < 10; ++j) s_ao[r][eg * 10 + j] = acc[j];
    }
    __syncthreads();

    {
        const int r = t >> 4, seg = t & 15;
        float p = 0.f;
        #pragma unroll
        for (int i = 0; i < 10; ++i) p = fmaf(s_ao[r][seg * 10 + i], mlp_w[seg * 10 + i], p);
        #pragma unroll
        for (int off = 1; off < 16; off <<= 1) p += __shfl_xor(p, off, 64);
        if (seg == 0) s_base[r] = p + mlp_b[0];
    }
    __syncthreads();

    #pragma unroll
    for (int c = 0; c < 10; ++c) {
        const int idx = t + 256 * c;
        out_ao[(long)b0 * DD + idx] = s_ao[idx / DD][idx % DD];
    }
    #pragma unroll
    for (int c = 0; c < 4; ++c) {
        const int idx = t + 256 * c;
        const int r = idx >> 6, kx = idx & 63;
        const float ew  = edge_weight[(long)(b0 + r) * KK + kx];
        const float val = fmaf(ew, mlp_w[DD], s_base[r]);
        out_new[(long)(b0 + r) * KK + kx] = (val >= 0.f) ? val : 0.01f * val;
    }
}

extern "C" void kernel_launch(void* const* d_in, const int* in_sizes, int n_in,
                              void* d_out, int out_size, void* d_ws, size_t ws_size,
                              hipStream_t stream) {
    const float* x   = (const float*)d_in[0];
    const int*   tni = (const int*)d_in[1];
    const int*   tnt = (const int*)d_in[2];
    const int*   nid = (const int*)d_in[3];
    const int*   et  = (const int*)d_in[4];
    const float* ew  = (const float*)d_in[5];
    const float* gu  = (const float*)d_in[6];
    const float* tew = (const float*)d_in[7];
    const float* teb = (const float*)d_in[8];
    const float* ipw = (const float*)d_in[9];
    const float* ipb = (const float*)d_in[10];
    const float* ow  = (const float*)d_in[11];
    const float* ob  = (const float*)d_in[12];
    const float* mw  = (const float*)d_in[13];
    const float* mb  = (const float*)d_in[14];

    float* wsf = (float*)d_ws;

    float* out      = (float*)d_out;
    float* out_ao   = out;
    float* out_new  = out + (long)NB * DD;
    float* out_mask = out + (long)NB * DD + (long)NB * KK;

    setup_kernel<<<(WS_WTOT + 255) / 256, 256, 0, stream>>>(ipw, ipb, ow, ob, wsf);
    qt_kernel<<<NB / 16, 256, 0, stream>>>(x, tni, tnt, tew, teb, wsf);
    attn_kernel<<<NB / TPB, 256, 0, stream>>>(x, nid, et, gu, tew, teb, wsf, out_mask);
    ao_kernel<<<NB / 16, 256, 0, stream>>>(ew, mw, mb, wsf, out_ao, out_new);
}